// Round 1
// baseline (2819.622 us; speedup 1.0000x reference)
//
#include <hip/hip_runtime.h>
#include <math.h>

// Problem constants (B=4, D=64, H=W=64 -> m=n=4096)
#define BB 4
#define DD 64
#define MM 4096
#define M1 4097
// norm = -log(m+n) = -log(8192); NORMC = +log(8192)
#define NORMC 9.0109133720f
// log_mu/log_nu bin entry: log(4096) - log(8192) = -log(2)
#define LOGHALF -0.69314718056f

// ---------------------------------------------------------------------------
// K1: couplings (euclidean cdist) -> G[b][i][j], i,j < 4096
// 64x64 output tile per block, 256 threads, full K=64 in LDS.
__global__ void __launch_bounds__(256)
couplings_kernel(const float* __restrict__ feat0,
                 const float* __restrict__ feat1,
                 float* __restrict__ G) {
    __shared__ float As[64][64];
    __shared__ float Bs[64][64];
    const int b  = blockIdx.z;
    const int i0 = blockIdx.y * 64;
    const int j0 = blockIdx.x * 64;
    const int tid = threadIdx.x;
    const int tx = tid & 15, ty = tid >> 4;

    const float* f0 = feat0 + (size_t)b * DD * MM;
    const float* f1 = feat1 + (size_t)b * DD * MM;

    // load 64 dims x 64 points per tile; feat layout [b][c][p], p fastest
#pragma unroll
    for (int l = 0; l < 16; ++l) {
        int idx = l * 256 + tid;   // 0..4095
        int c = idx >> 6;
        int p = idx & 63;
        As[c][p] = f0[c * MM + i0 + p];
        Bs[c][p] = f1[c * MM + j0 + p];
    }
    __syncthreads();

    float acc[4][4] = {};
    float ax2[4] = {};
    float by2[4] = {};
#pragma unroll
    for (int c = 0; c < 64; ++c) {
        float a[4], bv[4];
#pragma unroll
        for (int r = 0; r < 4; ++r) a[r] = As[c][ty + 16 * r];
#pragma unroll
        for (int s = 0; s < 4; ++s) bv[s] = Bs[c][tx + 16 * s];
#pragma unroll
        for (int r = 0; r < 4; ++r) ax2[r] += a[r] * a[r];
#pragma unroll
        for (int s = 0; s < 4; ++s) by2[s] += bv[s] * bv[s];
#pragma unroll
        for (int r = 0; r < 4; ++r)
#pragma unroll
            for (int s = 0; s < 4; ++s)
                acc[r][s] += a[r] * bv[s];
    }

    float* Gb = G + (size_t)b * M1 * M1;
#pragma unroll
    for (int r = 0; r < 4; ++r) {
        int i = i0 + ty + 16 * r;
#pragma unroll
        for (int s = 0; s < 4; ++s) {
            int j = j0 + tx + 16 * s;
            float d2 = ax2[r] + by2[s] - 2.0f * acc[r][s];
            d2 = fmaxf(d2, 0.0f);
            Gb[(size_t)i * M1 + j] = sqrtf(d2);
        }
    }
}

// ---------------------------------------------------------------------------
// K1b: fill dustbin row (i=4096, all j) and dustbin col (j=4096, i<4096)
__global__ void binfill_kernel(float* __restrict__ G, const float* __restrict__ bin) {
    const float bs = *bin;
    int t = blockIdx.x * blockDim.x + threadIdx.x;
    const int totalRow = BB * M1;   // last row entries
    const int totalCol = BB * MM;   // last col entries (i<4096)
    if (t < totalRow) {
        int b = t / M1, j = t % M1;
        G[((size_t)b * M1 + MM) * M1 + j] = bs;
    } else if (t < totalRow + totalCol) {
        int q = t - totalRow;
        int b = q / MM, i = q % MM;
        G[((size_t)b * M1 + i) * M1 + MM] = bs;
    }
}

// ---------------------------------------------------------------------------
// K2: u[b][i] = log_mu[i] - logsumexp_j(G[b][i][j] + v[b][j])
// one block per row
__global__ void __launch_bounds__(256)
u_update(const float* __restrict__ G, const float* __restrict__ v,
         float* __restrict__ u) {
    const int row = blockIdx.x;            // 0..BB*M1-1
    const int b = row / M1, i = row % M1;
    const float* Grow = G + ((size_t)b * M1 + i) * M1;
    const float* vb = v + b * M1;
    const int tid = threadIdx.x;

    float m = -INFINITY, s = 0.0f;
    for (int j = tid; j < M1; j += 256) {
        float val = Grow[j] + vb[j];
        if (val > m) { s = s * __expf(m - val) + 1.0f; m = val; }
        else         { s += __expf(val - m); }
    }
    // wave butterfly reduce (64 lanes)
#pragma unroll
    for (int off = 1; off < 64; off <<= 1) {
        float m2 = __shfl_xor(m, off);
        float s2 = __shfl_xor(s, off);
        float M = fmaxf(m, m2);
        s = s * __expf(m - M) + s2 * __expf(m2 - M);
        m = M;
    }
    __shared__ float sm[4], ss[4];
    if ((tid & 63) == 0) { sm[tid >> 6] = m; ss[tid >> 6] = s; }
    __syncthreads();
    if (tid == 0) {
        float M = sm[0], S = ss[0];
#pragma unroll
        for (int k = 1; k < 4; ++k) {
            float M2 = fmaxf(M, sm[k]);
            S = S * __expf(M - M2) + ss[k] * __expf(sm[k] - M2);
            M = M2;
        }
        float lse = M + __logf(S);
        float log_mu = (i < MM) ? -NORMC : LOGHALF;
        u[b * M1 + i] = log_mu - lse;
    }
}

// ---------------------------------------------------------------------------
// K3a: partial column logsumexp over row-chunks of 513 rows
// grid (17, 8, 4), 256 threads; thread owns one column within chunk
__global__ void __launch_bounds__(256)
v_partial(const float* __restrict__ G, const float* __restrict__ u,
          float* __restrict__ pmax, float* __restrict__ psum) {
    const int b = blockIdx.z;
    const int j = blockIdx.x * 256 + threadIdx.x;
    const int ic = blockIdx.y;
    const int i0 = ic * 513;
    const int i1 = min(i0 + 513, M1);

    float m = -INFINITY, s = 0.0f;
    if (j < M1) {
        const float* ub = u + b * M1;
        const float* Gb = G + (size_t)b * M1 * M1;
        for (int i = i0; i < i1; ++i) {
            float val = Gb[(size_t)i * M1 + j] + ub[i];
            if (val > m) { s = s * __expf(m - val) + 1.0f; m = val; }
            else         { s += __expf(val - m); }
        }
    }
    int idx = (b * 8 + ic) * 4352 + blockIdx.x * 256 + threadIdx.x;
    pmax[idx] = m;
    psum[idx] = s;
}

// K3b: combine 8 partials per column -> v
__global__ void __launch_bounds__(256)
v_combine(const float* __restrict__ pmax, const float* __restrict__ psum,
          float* __restrict__ v) {
    int t = blockIdx.x * blockDim.x + threadIdx.x;
    if (t >= BB * M1) return;
    int b = t / M1, j = t % M1;
    float M = -INFINITY, S = 0.0f;
#pragma unroll
    for (int ic = 0; ic < 8; ++ic) {
        int idx = (b * 8 + ic) * 4352 + j;
        float m = pmax[idx], s = psum[idx];
        float M2 = fmaxf(M, m);
        S = S * __expf(M - M2) + s * __expf(m - M2);
        M = M2;
    }
    float lse = M + __logf(S);
    float log_nu = (j < MM) ? -NORMC : LOGHALF;
    v[b * M1 + j] = log_nu - lse;
}

// ---------------------------------------------------------------------------
// K4: gamma = exp(Z0 + u + v + NORMC), write in place; per-block loss partials
__global__ void __launch_bounds__(256)
finalize_kernel(float* __restrict__ G, const float* __restrict__ u,
                const float* __restrict__ v, float* __restrict__ partials) {
    const int row = blockIdx.x;
    const int b = row / M1, i = row % M1;
    float* Grow = G + ((size_t)b * M1 + i) * M1;
    const float* vb = v + b * M1;
    const float ui = u[b * M1 + i];
    const int tid = threadIdx.x;

    float pm = 0.0f, pc = 0.0f, pr = 0.0f;
    for (int j = tid; j < M1; j += 256) {
        float z0 = Grow[j];
        float g = __expf(z0 + ui + vb[j] + NORMC);
        if (i < MM) {
            pr += g;                       // gamma[:, :-1, :]
            if (j < MM) pm += g * z0;      // gamma[:, :-1, :-1] * distance
        }
        if (j == MM) pc += g;              // gamma[:, :, -1]
        Grow[j] = g;
    }
#pragma unroll
    for (int off = 1; off < 64; off <<= 1) {
        pm += __shfl_xor(pm, off);
        pc += __shfl_xor(pc, off);
        pr += __shfl_xor(pr, off);
    }
    __shared__ float s0[4], s1[4], s2[4];
    if ((tid & 63) == 0) { int w = tid >> 6; s0[w] = pm; s1[w] = pc; s2[w] = pr; }
    __syncthreads();
    if (tid == 0) {
        float a = s0[0] + s0[1] + s0[2] + s0[3];
        float c = s1[0] + s1[1] + s1[2] + s1[3];
        float r = s2[0] + s2[1] + s2[2] + s2[3];
        partials[row * 3 + 0] = a;
        partials[row * 3 + 1] = c;
        partials[row * 3 + 2] = r;
    }
}

// K5: deterministic final reduction -> out[0], out[1]
__global__ void __launch_bounds__(256)
reduce_out(const float* __restrict__ partials, float* __restrict__ out) {
    const int tid = threadIdx.x;
    float s0 = 0.0f, s1 = 0.0f, s2 = 0.0f;
    for (int r = tid; r < BB * M1; r += 256) {
        s0 += partials[r * 3 + 0];
        s1 += partials[r * 3 + 1];
        s2 += partials[r * 3 + 2];
    }
#pragma unroll
    for (int off = 1; off < 64; off <<= 1) {
        s0 += __shfl_xor(s0, off);
        s1 += __shfl_xor(s1, off);
        s2 += __shfl_xor(s2, off);
    }
    __shared__ float a0[4], a1[4], a2[4];
    if ((tid & 63) == 0) { int w = tid >> 6; a0[w] = s0; a1[w] = s1; a2[w] = s2; }
    __syncthreads();
    if (tid == 0) {
        float S0 = a0[0] + a0[1] + a0[2] + a0[3];
        float S1 = a1[0] + a1[1] + a1[2] + a1[3];
        float S2 = a2[0] + a2[1] + a2[2] + a2[3];
        out[0] = S0 / (4.0f * 4096.0f);
        out[1] = S1 / (4.0f * 4097.0f) + S2 / (4.0f * 4096.0f * 4097.0f);
    }
}

// ---------------------------------------------------------------------------
extern "C" void kernel_launch(void* const* d_in, const int* in_sizes, int n_in,
                              void* d_out, int out_size, void* d_ws, size_t ws_size,
                              hipStream_t stream) {
    const float* feat0 = (const float*)d_in[0];
    const float* feat1 = (const float*)d_in[1];
    const float* bin   = (const float*)d_in[2];
    float* out = (float*)d_out;
    float* G   = out + 2;                // Z / gamma region: [4][4097][4097]

    float* ws = (float*)d_ws;
    float* u        = ws;                 // 16388
    float* v        = ws + 16388;         // 16388
    float* partials = ws + 32776;         // 49164
    float* pmax     = ws + 81940;         // 4*8*4352 = 139264
    float* psum     = ws + 221204;        // 139264   (total 360468 floats)

    // zero u, v (needed: v starts at 0)
    hipMemsetAsync(ws, 0, 32776 * sizeof(float), stream);

    couplings_kernel<<<dim3(64, 64, 4), 256, 0, stream>>>(feat0, feat1, G);
    binfill_kernel<<<(BB * M1 + BB * MM + 255) / 256, 256, 0, stream>>>(G, bin);

    for (int it = 0; it < 10; ++it) {
        u_update<<<BB * M1, 256, 0, stream>>>(G, v, u);
        v_partial<<<dim3(17, 8, BB), 256, 0, stream>>>(G, u, pmax, psum);
        v_combine<<<(BB * M1 + 255) / 256, 256, 0, stream>>>(pmax, psum, v);
    }

    finalize_kernel<<<BB * M1, 256, 0, stream>>>(G, u, v, partials);
    reduce_out<<<1, 256, 0, stream>>>(partials, out);
}

// Round 2
// 1920.863 us; speedup vs baseline: 1.4679x; 1.4679x over previous
//
#include <hip/hip_runtime.h>
#include <math.h>

// Problem constants (B=4, D=64, H=W=64 -> m=n=4096)
#define BB 4
#define DD 64
#define MM 4096
#define M1 4097
#define NORMC 9.0109133472792788f    // log(8192)
#define LOGHALF -0.69314718055994531f

typedef __attribute__((ext_vector_type(8))) short bf16x8;
typedef __attribute__((ext_vector_type(4))) float f32x4;

__device__ __forceinline__ f32x4 mfma16(bf16x8 a, bf16x8 b, f32x4 c) {
    return __builtin_amdgcn_mfma_f32_16x16x32_bf16(a, b, c, 0, 0, 0);
}
__device__ __forceinline__ unsigned short f2bf(float x) {
    unsigned u = __float_as_uint(x);
    u += 0x7fffu + ((u >> 16) & 1u);
    return (unsigned short)(u >> 16);
}
__device__ __forceinline__ float bf2f(unsigned short h) {
    return __uint_as_float(((unsigned)h) << 16);
}
__device__ __forceinline__ void lse_merge(float& m, float& s, float m2, float s2) {
    float M = fmaxf(m, m2);
    s = s * __expf(m - M) + s2 * __expf(m2 - M);
    m = M;
}
__device__ __forceinline__ void lse_add(float& m, float& s, float val) {
    float M = fmaxf(m, val);
    s = s * __expf(m - M) + __expf(val - M);
    m = M;
}

// ===========================================================================
// FAST PATH: recompute distances via split-precision bf16 MFMA every pass
// ===========================================================================

// Transpose [b][c][p] f32 -> [b][p][c] bf16 hi/lo split
__global__ void __launch_bounds__(256)
prep_kernel(const float* __restrict__ f0, const float* __restrict__ f1,
            unsigned short* __restrict__ h0, unsigned short* __restrict__ l0,
            unsigned short* __restrict__ h1, unsigned short* __restrict__ l1) {
    __shared__ float T[64][65];
    const int b = blockIdx.y;
    const int p0 = blockIdx.x * 64;
    const float* src = (blockIdx.z == 0 ? f0 : f1) + (size_t)b * DD * MM;
    unsigned short* dh = (blockIdx.z == 0 ? h0 : h1) + (size_t)b * MM * DD;
    unsigned short* dl = (blockIdx.z == 0 ? l0 : l1) + (size_t)b * MM * DD;
    const int tid = threadIdx.x;
#pragma unroll
    for (int l = 0; l < 16; ++l) {
        int idx = l * 256 + tid;
        T[idx >> 6][idx & 63] = src[(idx >> 6) * MM + p0 + (idx & 63)];
    }
    __syncthreads();
    const int p = tid >> 2;
    const int cs = (tid & 3) * 16;
    unsigned hw[8], lw[8];
#pragma unroll
    for (int k = 0; k < 8; ++k) {
        float x0 = T[cs + 2 * k][p], x1 = T[cs + 2 * k + 1][p];
        unsigned short a = f2bf(x0), c = f2bf(x1);
        hw[k] = (unsigned)a | ((unsigned)c << 16);
        unsigned short ra = f2bf(x0 - bf2f(a)), rc = f2bf(x1 - bf2f(c));
        lw[k] = (unsigned)ra | ((unsigned)rc << 16);
    }
    size_t base = (size_t)(p0 + p) * DD + cs;
    *(uint4*)(dh + base)     = make_uint4(hw[0], hw[1], hw[2], hw[3]);
    *(uint4*)(dh + base + 8) = make_uint4(hw[4], hw[5], hw[6], hw[7]);
    *(uint4*)(dl + base)     = make_uint4(lw[0], lw[1], lw[2], lw[3]);
    *(uint4*)(dl + base + 8) = make_uint4(lw[4], lw[5], lw[6], lw[7]);
}

// Exact f32 squared norms from original inputs
__global__ void __launch_bounds__(256)
norms_kernel(const float* __restrict__ f0, const float* __restrict__ f1,
             float* __restrict__ n0, float* __restrict__ n1) {
    int t = blockIdx.x * 256 + threadIdx.x;   // over BB*MM
    if (t >= BB * MM) return;
    int b = t / MM, p = t % MM;
    const float* s0 = f0 + (size_t)b * DD * MM + p;
    const float* s1 = f1 + (size_t)b * DD * MM + p;
    float a = 0.f, c = 0.f;
#pragma unroll 8
    for (int k = 0; k < DD; ++k) {
        float x = s0[(size_t)k * MM]; a = fmaf(x, x, a);
        float y = s1[(size_t)k * MM]; c = fmaf(y, y, c);
    }
    n0[t] = a; n1[t] = c;
}

// u[b][i] = log_mu - lse_j( dist(i,j) + v[j] ), 32 rows/block, 4-wave j-split
__global__ void __launch_bounds__(256)
upass_kernel(const unsigned short* __restrict__ h0, const unsigned short* __restrict__ l0,
             const unsigned short* __restrict__ h1, const unsigned short* __restrict__ l1,
             const float* __restrict__ n0, const float* __restrict__ n1,
             const float* __restrict__ v, float* __restrict__ u,
             const float* __restrict__ bin) {
    const int id = blockIdx.x;                 // 0..511, XCD-swizzled
    const int xcd = id & 7, slot = id >> 3;
    const int b = xcd >> 1;
    const int x = slot * 2 + (xcd & 1);        // 0..127
    const int r0 = x * 32;
    const float bs = *bin;
    const float* vb = v + b * M1;
    const int tid = threadIdx.x;
    const int w = tid >> 6, l = tid & 63, lg = l >> 4, lc = l & 15;
    const size_t fb = (size_t)b * MM * DD;

    bf16x8 Ah[2][2], Al[2][2];
#pragma unroll
    for (int st = 0; st < 2; ++st) {
        const unsigned short* pa = h0 + fb + (size_t)(r0 + st * 16 + lc) * DD + 8 * lg;
        const unsigned short* qa = l0 + fb + (size_t)(r0 + st * 16 + lc) * DD + 8 * lg;
        Ah[st][0] = *(const bf16x8*)pa; Ah[st][1] = *(const bf16x8*)(pa + 32);
        Al[st][0] = *(const bf16x8*)qa; Al[st][1] = *(const bf16x8*)(qa + 32);
    }
    float n0r[2][4], m[2][4], s[2][4];
#pragma unroll
    for (int st = 0; st < 2; ++st)
#pragma unroll
        for (int e = 0; e < 4; ++e) {
            n0r[st][e] = n0[b * MM + r0 + st * 16 + 4 * lg + e];
            m[st][e] = -INFINITY; s[st][e] = 0.f;
        }

    for (int tt = 0; tt < 64; ++tt) {
        const int j0 = w * 1024 + tt * 16;
        const unsigned short* pb = h1 + fb + (size_t)(j0 + lc) * DD + 8 * lg;
        const unsigned short* qb = l1 + fb + (size_t)(j0 + lc) * DD + 8 * lg;
        bf16x8 Bh0 = *(const bf16x8*)pb, Bh1 = *(const bf16x8*)(pb + 32);
        bf16x8 Bl0 = *(const bf16x8*)qb, Bl1 = *(const bf16x8*)(qb + 32);
        float n1j = n1[b * MM + j0 + lc];
        float vj = vb[j0 + lc];
#pragma unroll
        for (int st = 0; st < 2; ++st) {
            f32x4 acc = {0.f, 0.f, 0.f, 0.f};
            acc = mfma16(Ah[st][0], Bh0, acc);
            acc = mfma16(Ah[st][1], Bh1, acc);
            acc = mfma16(Ah[st][0], Bl0, acc);
            acc = mfma16(Ah[st][1], Bl1, acc);
            acc = mfma16(Al[st][0], Bh0, acc);
            acc = mfma16(Al[st][1], Bh1, acc);
#pragma unroll
            for (int e = 0; e < 4; ++e) {
                float d2 = fmaxf(__builtin_fmaf(-2.f, acc[e], n0r[st][e] + n1j), 0.f);
                float val = sqrtf(d2) + vj;
                lse_add(m[st][e], s[st][e], val);
            }
        }
    }
#pragma unroll
    for (int off = 1; off < 16; off <<= 1)
#pragma unroll
        for (int st = 0; st < 2; ++st)
#pragma unroll
            for (int e = 0; e < 4; ++e)
                lse_merge(m[st][e], s[st][e], __shfl_xor(m[st][e], off), __shfl_xor(s[st][e], off));

    __shared__ float lm[4][32], lsx[4][32];
    if (lc == 0) {
#pragma unroll
        for (int st = 0; st < 2; ++st)
#pragma unroll
            for (int e = 0; e < 4; ++e) {
                lm[w][st * 16 + 4 * lg + e] = m[st][e];
                lsx[w][st * 16 + 4 * lg + e] = s[st][e];
            }
    }
    __syncthreads();
    if (tid < 32) {
        float M = lm[0][tid], S = lsx[0][tid];
#pragma unroll
        for (int k = 1; k < 4; ++k) lse_merge(M, S, lm[k][tid], lsx[k][tid]);
        lse_add(M, S, bs + vb[MM]);            // dustbin column entry
        u[b * M1 + r0 + tid] = -NORMC - (M + __logf(S));
    }
    if (x == 0) {                               // dustbin row: u[b][4096]
        float dm = -INFINITY, dsv = 0.f;
        for (int j = tid; j < M1; j += 256) lse_add(dm, dsv, vb[j]);
#pragma unroll
        for (int off = 1; off < 64; off <<= 1)
            lse_merge(dm, dsv, __shfl_xor(dm, off), __shfl_xor(dsv, off));
        __shared__ float am[4], asv[4];
        if (l == 0) { am[w] = dm; asv[w] = dsv; }
        __syncthreads();
        if (tid == 0) {
            float M = am[0], S = asv[0];
#pragma unroll
            for (int k = 1; k < 4; ++k) lse_merge(M, S, am[k], asv[k]);
            u[b * M1 + MM] = LOGHALF - (bs + M + __logf(S));
        }
    }
}

// v[b][j] = log_nu - lse_i( dist(i,j) + u[i] ), 32 cols/block, 4-wave i-split
__global__ void __launch_bounds__(256)
vpass_kernel(const unsigned short* __restrict__ h0, const unsigned short* __restrict__ l0,
             const unsigned short* __restrict__ h1, const unsigned short* __restrict__ l1,
             const float* __restrict__ n0, const float* __restrict__ n1,
             const float* __restrict__ u, float* __restrict__ v,
             const float* __restrict__ bin) {
    const int id = blockIdx.x;
    const int xcd = id & 7, slot = id >> 3;
    const int b = xcd >> 1;
    const int x = slot * 2 + (xcd & 1);
    const int j0 = x * 32;
    const float bs = *bin;
    const float* ub = u + b * M1;
    const int tid = threadIdx.x;
    const int w = tid >> 6, l = tid & 63, lg = l >> 4, lc = l & 15;
    const size_t fb = (size_t)b * MM * DD;

    bf16x8 Bh[2][2], Bl[2][2];
#pragma unroll
    for (int st = 0; st < 2; ++st) {
        const unsigned short* pb = h1 + fb + (size_t)(j0 + st * 16 + lc) * DD + 8 * lg;
        const unsigned short* qb = l1 + fb + (size_t)(j0 + st * 16 + lc) * DD + 8 * lg;
        Bh[st][0] = *(const bf16x8*)pb; Bh[st][1] = *(const bf16x8*)(pb + 32);
        Bl[st][0] = *(const bf16x8*)qb; Bl[st][1] = *(const bf16x8*)(qb + 32);
    }
    float n1c[2] = { n1[b * MM + j0 + lc], n1[b * MM + j0 + 16 + lc] };
    float m[2] = { -INFINITY, -INFINITY }, s[2] = { 0.f, 0.f };

    for (int tt = 0; tt < 64; ++tt) {
        const int i0 = w * 1024 + tt * 16;
        const unsigned short* pa = h0 + fb + (size_t)(i0 + lc) * DD + 8 * lg;
        const unsigned short* qa = l0 + fb + (size_t)(i0 + lc) * DD + 8 * lg;
        bf16x8 Ah0 = *(const bf16x8*)pa, Ah1 = *(const bf16x8*)(pa + 32);
        bf16x8 Al0 = *(const bf16x8*)qa, Al1 = *(const bf16x8*)(qa + 32);
        float uw[4], nw[4];
#pragma unroll
        for (int e = 0; e < 4; ++e) {
            int row = i0 + 4 * lg + e;
            uw[e] = ub[row];
            nw[e] = n0[b * MM + row];
        }
#pragma unroll
        for (int st = 0; st < 2; ++st) {
            f32x4 acc = {0.f, 0.f, 0.f, 0.f};
            acc = mfma16(Ah0, Bh[st][0], acc);
            acc = mfma16(Ah1, Bh[st][1], acc);
            acc = mfma16(Ah0, Bl[st][0], acc);
            acc = mfma16(Ah1, Bl[st][1], acc);
            acc = mfma16(Al0, Bh[st][0], acc);
            acc = mfma16(Al1, Bh[st][1], acc);
#pragma unroll
            for (int e = 0; e < 4; ++e) {
                float d2 = fmaxf(__builtin_fmaf(-2.f, acc[e], nw[e] + n1c[st]), 0.f);
                float val = sqrtf(d2) + uw[e];
                lse_add(m[st], s[st], val);
            }
        }
    }
    // combine across the 4 lane-groups (rows within tile): lanes l, l^16, l^32, l^48
#pragma unroll
    for (int off = 16; off < 64; off <<= 1)
#pragma unroll
        for (int st = 0; st < 2; ++st)
            lse_merge(m[st], s[st], __shfl_xor(m[st], off), __shfl_xor(s[st], off));

    __shared__ float lmv[4][2][16], lsv[4][2][16];
    if (l < 16) {
#pragma unroll
        for (int st = 0; st < 2; ++st) { lmv[w][st][l] = m[st]; lsv[w][st][l] = s[st]; }
    }
    __syncthreads();
    if (tid < 32) {
        int st = tid >> 4, c = tid & 15;
        float M = lmv[0][st][c], S = lsv[0][st][c];
#pragma unroll
        for (int k = 1; k < 4; ++k) lse_merge(M, S, lmv[k][st][c], lsv[k][st][c]);
        lse_add(M, S, bs + ub[MM]);            // dustbin row entry
        v[b * M1 + j0 + st * 16 + c] = -NORMC - (M + __logf(S));
    }
    if (x == 0) {                               // dustbin col: v[b][4096]
        float dm = -INFINITY, dsv = 0.f;
        for (int i = tid; i < M1; i += 256) lse_add(dm, dsv, ub[i]);
#pragma unroll
        for (int off = 1; off < 64; off <<= 1)
            lse_merge(dm, dsv, __shfl_xor(dm, off), __shfl_xor(dsv, off));
        __shared__ float am[4], asv[4];
        if (l == 0) { am[w] = dm; asv[w] = dsv; }
        __syncthreads();
        if (tid == 0) {
            float M = am[0], S = asv[0];
#pragma unroll
            for (int k = 1; k < 4; ++k) lse_merge(M, S, am[k], asv[k]);
            v[b * M1 + MM] = LOGHALF - (bs + M + __logf(S));
        }
    }
}

// gamma main region (i<4096, j<4096): recompute dist, exp, write, loss partials
__global__ void __launch_bounds__(256)
fin_main_kernel(const unsigned short* __restrict__ h0, const unsigned short* __restrict__ l0,
                const unsigned short* __restrict__ h1, const unsigned short* __restrict__ l1,
                const float* __restrict__ n0, const float* __restrict__ n1,
                const float* __restrict__ u, const float* __restrict__ v,
                float* __restrict__ G, float* __restrict__ pA) {
    const int id = blockIdx.x;
    const int xcd = id & 7, slot = id >> 3;
    const int b = xcd >> 1;
    const int x = slot * 2 + (xcd & 1);
    const int r0 = x * 32;
    const float* vb = v + b * M1;
    const int tid = threadIdx.x;
    const int w = tid >> 6, l = tid & 63, lg = l >> 4, lc = l & 15;
    const size_t fb = (size_t)b * MM * DD;

    bf16x8 Ah[2][2], Al[2][2];
#pragma unroll
    for (int st = 0; st < 2; ++st) {
        const unsigned short* pa = h0 + fb + (size_t)(r0 + st * 16 + lc) * DD + 8 * lg;
        const unsigned short* qa = l0 + fb + (size_t)(r0 + st * 16 + lc) * DD + 8 * lg;
        Ah[st][0] = *(const bf16x8*)pa; Ah[st][1] = *(const bf16x8*)(pa + 32);
        Al[st][0] = *(const bf16x8*)qa; Al[st][1] = *(const bf16x8*)(qa + 32);
    }
    float n0r[2][4], ur[2][4];
#pragma unroll
    for (int st = 0; st < 2; ++st)
#pragma unroll
        for (int e = 0; e < 4; ++e) {
            int row = r0 + st * 16 + 4 * lg + e;
            n0r[st][e] = n0[b * MM + row];
            ur[st][e] = u[b * M1 + row];
        }
    float pm = 0.f, pr = 0.f;
    for (int tt = 0; tt < 64; ++tt) {
        const int j0 = w * 1024 + tt * 16;
        const unsigned short* pb = h1 + fb + (size_t)(j0 + lc) * DD + 8 * lg;
        const unsigned short* qb = l1 + fb + (size_t)(j0 + lc) * DD + 8 * lg;
        bf16x8 Bh0 = *(const bf16x8*)pb, Bh1 = *(const bf16x8*)(pb + 32);
        bf16x8 Bl0 = *(const bf16x8*)qb, Bl1 = *(const bf16x8*)(qb + 32);
        float n1j = n1[b * MM + j0 + lc];
        float vj = vb[j0 + lc];
#pragma unroll
        for (int st = 0; st < 2; ++st) {
            f32x4 acc = {0.f, 0.f, 0.f, 0.f};
            acc = mfma16(Ah[st][0], Bh0, acc);
            acc = mfma16(Ah[st][1], Bh1, acc);
            acc = mfma16(Ah[st][0], Bl0, acc);
            acc = mfma16(Ah[st][1], Bl1, acc);
            acc = mfma16(Al[st][0], Bh0, acc);
            acc = mfma16(Al[st][1], Bh1, acc);
#pragma unroll
            for (int e = 0; e < 4; ++e) {
                float d2 = fmaxf(__builtin_fmaf(-2.f, acc[e], n0r[st][e] + n1j), 0.f);
                float d = sqrtf(d2);
                float g = __expf(d + ur[st][e] + vj + NORMC);
                int row = r0 + st * 16 + 4 * lg + e;
                G[((size_t)(b * M1 + row)) * M1 + j0 + lc] = g;
                pm = fmaf(g, d, pm);
                pr += g;
            }
        }
    }
#pragma unroll
    for (int off = 1; off < 64; off <<= 1) {
        pm += __shfl_xor(pm, off);
        pr += __shfl_xor(pr, off);
    }
    __shared__ float s0[4], s1[4];
    if (l == 0) { s0[w] = pm; s1[w] = pr; }
    __syncthreads();
    if (tid == 0) {
        pA[id * 2 + 0] = s0[0] + s0[1] + s0[2] + s0[3];
        pA[id * 2 + 1] = s1[0] + s1[1] + s1[2] + s1[3];
    }
}

// last row + last col + corner of gamma, with loss partials
__global__ void __launch_bounds__(256)
fin_edge_kernel(const float* __restrict__ u, const float* __restrict__ v,
                const float* __restrict__ bin, float* __restrict__ G,
                float* __restrict__ pB) {
    const float bs = *bin;
    int t = blockIdx.x * 256 + threadIdx.x;
    float pc = 0.f, pr = 0.f;
    if (t < BB * M1) {
        int b = t / M1, j = t % M1;
        float g = __expf(bs + u[b * M1 + MM] + v[b * M1 + j] + NORMC);
        G[((size_t)b * M1 + MM) * M1 + j] = g;
        if (j == MM) pc += g;                  // corner (in gamma[:,:,-1])
    } else if (t < BB * M1 + BB * MM) {
        int q = t - BB * M1;
        int b = q / MM, i = q % MM;
        float g = __expf(bs + u[b * M1 + i] + v[b * M1 + MM] + NORMC);
        G[((size_t)b * M1 + i) * M1 + MM] = g;
        pc += g;                                // gamma[:, :, -1], i<4096
        pr += g;                                // gamma[:, :-1, :] last-col part
    }
#pragma unroll
    for (int off = 1; off < 64; off <<= 1) {
        pc += __shfl_xor(pc, off);
        pr += __shfl_xor(pr, off);
    }
    __shared__ float s0[4], s1[4];
    int tid = threadIdx.x;
    if ((tid & 63) == 0) { s0[tid >> 6] = pc; s1[tid >> 6] = pr; }
    __syncthreads();
    if (tid == 0) {
        pB[blockIdx.x * 2 + 0] = s0[0] + s0[1] + s0[2] + s0[3];
        pB[blockIdx.x * 2 + 1] = s1[0] + s1[1] + s1[2] + s1[3];
    }
}

__global__ void __launch_bounds__(256)
reduce_out_kernel(const float* __restrict__ pA, const float* __restrict__ pB,
                  float* __restrict__ out) {
    const int tid = threadIdx.x;
    float pm = 0.f, prA = 0.f, pc = 0.f, prB = 0.f;
    for (int r = tid; r < 512; r += 256) { pm += pA[2 * r]; prA += pA[2 * r + 1]; }
    if (tid < 129) { pc = pB[2 * tid]; prB = pB[2 * tid + 1]; }
#pragma unroll
    for (int off = 1; off < 64; off <<= 1) {
        pm += __shfl_xor(pm, off);
        prA += __shfl_xor(prA, off);
        pc += __shfl_xor(pc, off);
        prB += __shfl_xor(prB, off);
    }
    __shared__ float a0[4], a1[4], a2[4], a3[4];
    if ((tid & 63) == 0) {
        int w = tid >> 6;
        a0[w] = pm; a1[w] = prA; a2[w] = pc; a3[w] = prB;
    }
    __syncthreads();
    if (tid == 0) {
        float PM = a0[0] + a0[1] + a0[2] + a0[3];
        float PRA = a1[0] + a1[1] + a1[2] + a1[3];
        float PC = a2[0] + a2[1] + a2[2] + a2[3];
        float PRB = a3[0] + a3[1] + a3[2] + a3[3];
        out[0] = PM / (4.0f * 4096.0f);
        out[1] = PC / (4.0f * 4097.0f) + (PRA + PRB) / (4.0f * 4096.0f * 4097.0f);
    }
}

// ===========================================================================
// FALLBACK PATH (round-1, materialized matrix) — used only if ws too small
// ===========================================================================
__global__ void __launch_bounds__(256)
couplings_kernel(const float* __restrict__ feat0, const float* __restrict__ feat1,
                 float* __restrict__ G) {
    __shared__ float As[64][64];
    __shared__ float Bs[64][64];
    const int b = blockIdx.z;
    const int i0 = blockIdx.y * 64;
    const int j0 = blockIdx.x * 64;
    const int tid = threadIdx.x;
    const int tx = tid & 15, ty = tid >> 4;
    const float* f0 = feat0 + (size_t)b * DD * MM;
    const float* f1 = feat1 + (size_t)b * DD * MM;
#pragma unroll
    for (int l = 0; l < 16; ++l) {
        int idx = l * 256 + tid;
        int c = idx >> 6, p = idx & 63;
        As[c][p] = f0[c * MM + i0 + p];
        Bs[c][p] = f1[c * MM + j0 + p];
    }
    __syncthreads();
    float acc[4][4] = {}, ax2[4] = {}, by2[4] = {};
#pragma unroll
    for (int c = 0; c < 64; ++c) {
        float a[4], bv[4];
#pragma unroll
        for (int r = 0; r < 4; ++r) a[r] = As[c][ty + 16 * r];
#pragma unroll
        for (int sx = 0; sx < 4; ++sx) bv[sx] = Bs[c][tx + 16 * sx];
#pragma unroll
        for (int r = 0; r < 4; ++r) ax2[r] += a[r] * a[r];
#pragma unroll
        for (int sx = 0; sx < 4; ++sx) by2[sx] += bv[sx] * bv[sx];
#pragma unroll
        for (int r = 0; r < 4; ++r)
#pragma unroll
            for (int sx = 0; sx < 4; ++sx) acc[r][sx] += a[r] * bv[sx];
    }
    float* Gb = G + (size_t)b * M1 * M1;
#pragma unroll
    for (int r = 0; r < 4; ++r) {
        int i = i0 + ty + 16 * r;
#pragma unroll
        for (int sx = 0; sx < 4; ++sx) {
            int j = j0 + tx + 16 * sx;
            float d2 = fmaxf(ax2[r] + by2[sx] - 2.0f * acc[r][sx], 0.0f);
            Gb[(size_t)i * M1 + j] = sqrtf(d2);
        }
    }
}

__global__ void binfill_kernel(float* __restrict__ G, const float* __restrict__ bin) {
    const float bs = *bin;
    int t = blockIdx.x * blockDim.x + threadIdx.x;
    const int totalRow = BB * M1;
    const int totalCol = BB * MM;
    if (t < totalRow) {
        int b = t / M1, j = t % M1;
        G[((size_t)b * M1 + MM) * M1 + j] = bs;
    } else if (t < totalRow + totalCol) {
        int q = t - totalRow;
        int b = q / MM, i = q % MM;
        G[((size_t)b * M1 + i) * M1 + MM] = bs;
    }
}

__global__ void __launch_bounds__(256)
u_update(const float* __restrict__ G, const float* __restrict__ v, float* __restrict__ u) {
    const int row = blockIdx.x;
    const int b = row / M1, i = row % M1;
    const float* Grow = G + ((size_t)b * M1 + i) * M1;
    const float* vb = v + b * M1;
    const int tid = threadIdx.x;
    float m = -INFINITY, s = 0.0f;
    for (int j = tid; j < M1; j += 256) lse_add(m, s, Grow[j] + vb[j]);
#pragma unroll
    for (int off = 1; off < 64; off <<= 1)
        lse_merge(m, s, __shfl_xor(m, off), __shfl_xor(s, off));
    __shared__ float sm[4], ss[4];
    if ((tid & 63) == 0) { sm[tid >> 6] = m; ss[tid >> 6] = s; }
    __syncthreads();
    if (tid == 0) {
        float M = sm[0], S = ss[0];
#pragma unroll
        for (int k = 1; k < 4; ++k) lse_merge(M, S, sm[k], ss[k]);
        float log_mu = (i < MM) ? -NORMC : LOGHALF;
        u[b * M1 + i] = log_mu - (M + __logf(S));
    }
}

__global__ void __launch_bounds__(256)
v_partial(const float* __restrict__ G, const float* __restrict__ u,
          float* __restrict__ pmax, float* __restrict__ psum) {
    const int b = blockIdx.z;
    const int j = blockIdx.x * 256 + threadIdx.x;
    const int ic = blockIdx.y;
    const int i0 = ic * 513;
    const int i1 = min(i0 + 513, M1);
    float m = -INFINITY, s = 0.0f;
    if (j < M1) {
        const float* ub = u + b * M1;
        const float* Gb = G + (size_t)b * M1 * M1;
        for (int i = i0; i < i1; ++i) lse_add(m, s, Gb[(size_t)i * M1 + j] + ub[i]);
    }
    int idx = (b * 8 + ic) * 4352 + blockIdx.x * 256 + threadIdx.x;
    pmax[idx] = m; psum[idx] = s;
}

__global__ void __launch_bounds__(256)
v_combine(const float* __restrict__ pmax, const float* __restrict__ psum,
          float* __restrict__ v) {
    int t = blockIdx.x * blockDim.x + threadIdx.x;
    if (t >= BB * M1) return;
    int b = t / M1, j = t % M1;
    float M = -INFINITY, S = 0.0f;
#pragma unroll
    for (int ic = 0; ic < 8; ++ic) {
        int idx = (b * 8 + ic) * 4352 + j;
        lse_merge(M, S, pmax[idx], psum[idx]);
    }
    float log_nu = (j < MM) ? -NORMC : LOGHALF;
    v[b * M1 + j] = log_nu - (M + __logf(S));
}

__global__ void __launch_bounds__(256)
finalize_kernel(float* __restrict__ G, const float* __restrict__ u,
                const float* __restrict__ v, float* __restrict__ partials) {
    const int row = blockIdx.x;
    const int b = row / M1, i = row % M1;
    float* Grow = G + ((size_t)b * M1 + i) * M1;
    const float* vb = v + b * M1;
    const float ui = u[b * M1 + i];
    const int tid = threadIdx.x;
    float pm = 0.0f, pc = 0.0f, pr = 0.0f;
    for (int j = tid; j < M1; j += 256) {
        float z0 = Grow[j];
        float g = __expf(z0 + ui + vb[j] + NORMC);
        if (i < MM) {
            pr += g;
            if (j < MM) pm += g * z0;
        }
        if (j == MM) pc += g;
        Grow[j] = g;
    }
#pragma unroll
    for (int off = 1; off < 64; off <<= 1) {
        pm += __shfl_xor(pm, off);
        pc += __shfl_xor(pc, off);
        pr += __shfl_xor(pr, off);
    }
    __shared__ float s0[4], s1[4], s2[4];
    if ((tid & 63) == 0) { int w = tid >> 6; s0[w] = pm; s1[w] = pc; s2[w] = pr; }
    __syncthreads();
    if (tid == 0) {
        partials[row * 3 + 0] = s0[0] + s0[1] + s0[2] + s0[3];
        partials[row * 3 + 1] = s1[0] + s1[1] + s1[2] + s1[3];
        partials[row * 3 + 2] = s2[0] + s2[1] + s2[2] + s2[3];
    }
}

__global__ void __launch_bounds__(256)
reduce_out(const float* __restrict__ partials, float* __restrict__ out) {
    const int tid = threadIdx.x;
    float s0 = 0.0f, s1 = 0.0f, s2 = 0.0f;
    for (int r = tid; r < BB * M1; r += 256) {
        s0 += partials[r * 3 + 0];
        s1 += partials[r * 3 + 1];
        s2 += partials[r * 3 + 2];
    }
#pragma unroll
    for (int off = 1; off < 64; off <<= 1) {
        s0 += __shfl_xor(s0, off);
        s1 += __shfl_xor(s1, off);
        s2 += __shfl_xor(s2, off);
    }
    __shared__ float a0[4], a1[4], a2[4];
    if ((tid & 63) == 0) { int w = tid >> 6; a0[w] = s0; a1[w] = s1; a2[w] = s2; }
    __syncthreads();
    if (tid == 0) {
        float S0 = a0[0] + a0[1] + a0[2] + a0[3];
        float S1 = a1[0] + a1[1] + a1[2] + a1[3];
        float S2 = a2[0] + a2[1] + a2[2] + a2[3];
        out[0] = S0 / (4.0f * 4096.0f);
        out[1] = S1 / (4.0f * 4097.0f) + S2 / (4.0f * 4096.0f * 4097.0f);
    }
}

// ===========================================================================
extern "C" void kernel_launch(void* const* d_in, const int* in_sizes, int n_in,
                              void* d_out, int out_size, void* d_ws, size_t ws_size,
                              hipStream_t stream) {
    const float* feat0 = (const float*)d_in[0];
    const float* feat1 = (const float*)d_in[1];
    const float* bin   = (const float*)d_in[2];
    float* out = (float*)d_out;
    float* G   = out + 2;                      // gamma region [4][4097][4097]
    float* ws  = (float*)d_ws;

    // fast-path ws layout (floats)
    const size_t OF_U = 0, OF_V = 16388, OF_N0 = 32776, OF_N1 = 49160;
    const size_t OF_PA = 65544, OF_PB = 66568, OF_BF = 66832;   // bf16 arrays after
    const size_t NEED = OF_BF * 4 + (size_t)4 * 1048576 * 2;    // ~8.66 MB

    if (ws_size >= NEED) {
        float* u  = ws + OF_U;
        float* v  = ws + OF_V;
        float* n0 = ws + OF_N0;
        float* n1 = ws + OF_N1;
        float* pA = ws + OF_PA;
        float* pB = ws + OF_PB;
        unsigned short* h0 = (unsigned short*)(ws + OF_BF);
        unsigned short* l0 = h0 + 1048576;
        unsigned short* h1 = l0 + 1048576;
        unsigned short* l1 = h1 + 1048576;

        hipMemsetAsync(ws, 0, 32776 * sizeof(float), stream);   // u, v = 0
        prep_kernel<<<dim3(64, BB, 2), 256, 0, stream>>>(feat0, feat1, h0, l0, h1, l1);
        norms_kernel<<<64, 256, 0, stream>>>(feat0, feat1, n0, n1);
        for (int it = 0; it < 10; ++it) {
            upass_kernel<<<512, 256, 0, stream>>>(h0, l0, h1, l1, n0, n1, v, u, bin);
            vpass_kernel<<<512, 256, 0, stream>>>(h0, l0, h1, l1, n0, n1, u, v, bin);
        }
        fin_main_kernel<<<512, 256, 0, stream>>>(h0, l0, h1, l1, n0, n1, u, v, G, pA);
        fin_edge_kernel<<<129, 256, 0, stream>>>(u, v, bin, G, pB);
        reduce_out_kernel<<<1, 256, 0, stream>>>(pA, pB, out);
    } else {
        // fallback: materialized-matrix algorithm (round 1)
        float* u        = ws;
        float* v        = ws + 16388;
        float* partials = ws + 32776;
        float* pmax     = ws + 81940;
        float* psum     = ws + 221204;
        hipMemsetAsync(ws, 0, 32776 * sizeof(float), stream);
        couplings_kernel<<<dim3(64, 64, 4), 256, 0, stream>>>(feat0, feat1, G);
        binfill_kernel<<<(BB * M1 + BB * MM + 255) / 256, 256, 0, stream>>>(G, bin);
        for (int it = 0; it < 10; ++it) {
            u_update<<<BB * M1, 256, 0, stream>>>(G, v, u);
            v_partial<<<dim3(17, 8, BB), 256, 0, stream>>>(G, u, pmax, psum);
            v_combine<<<(BB * M1 + 255) / 256, 256, 0, stream>>>(pmax, psum, v);
        }
        finalize_kernel<<<BB * M1, 256, 0, stream>>>(G, u, v, partials);
        reduce_out<<<1, 256, 0, stream>>>(partials, out);
    }
}

// Round 3
// 721.788 us; speedup vs baseline: 3.9064x; 2.6613x over previous
//
#include <hip/hip_runtime.h>
#include <math.h>

// Problem constants (B=4, D=64, H=W=64 -> m=n=4096)
#define BB 4
#define DD 64
#define MM 4096
#define M1 4097
#define UVST 4104                     // padded u/v row stride (16B-aligned)
#define NORMC 9.0109133472792788f     // log(8192)
#define LOGHALF -0.69314718055994531f
#define CSH 12.0f                     // fixed LSE shift (see analysis)

typedef __attribute__((ext_vector_type(8))) short bf16x8;
typedef __attribute__((ext_vector_type(4))) float f32x4;
typedef __attribute__((ext_vector_type(8))) _Float16 half8;

__device__ __forceinline__ f32x4 mfma16(bf16x8 a, bf16x8 b, f32x4 c) {
    return __builtin_amdgcn_mfma_f32_16x16x32_bf16(a, b, c, 0, 0, 0);
}
__device__ __forceinline__ unsigned short f2bf(float x) {
    unsigned u = __float_as_uint(x);
    u += 0x7fffu + ((u >> 16) & 1u);
    return (unsigned short)(u >> 16);
}
__device__ __forceinline__ float bf2f(unsigned short h) {
    return __uint_as_float(((unsigned)h) << 16);
}
__device__ __forceinline__ void lse_merge(float& m, float& s, float m2, float s2) {
    float M = fmaxf(m, m2);
    s = s * __expf(m - M) + s2 * __expf(m2 - M);
    m = M;
}
__device__ __forceinline__ void lse_add(float& m, float& s, float val) {
    float M = fmaxf(m, val);
    s = s * __expf(m - M) + __expf(val - M);
    m = M;
}

// ===========================================================================
// Shared prep: bf16 hi/lo transposed feats + exact f32 norms
// ===========================================================================
__global__ void __launch_bounds__(256)
prep_kernel(const float* __restrict__ f0, const float* __restrict__ f1,
            unsigned short* __restrict__ h0, unsigned short* __restrict__ l0,
            unsigned short* __restrict__ h1, unsigned short* __restrict__ l1) {
    __shared__ float T[64][65];
    const int b = blockIdx.y;
    const int p0 = blockIdx.x * 64;
    const float* src = (blockIdx.z == 0 ? f0 : f1) + (size_t)b * DD * MM;
    unsigned short* dh = (blockIdx.z == 0 ? h0 : h1) + (size_t)b * MM * DD;
    unsigned short* dl = (blockIdx.z == 0 ? l0 : l1) + (size_t)b * MM * DD;
    const int tid = threadIdx.x;
#pragma unroll
    for (int l = 0; l < 16; ++l) {
        int idx = l * 256 + tid;
        T[idx >> 6][idx & 63] = src[(idx >> 6) * MM + p0 + (idx & 63)];
    }
    __syncthreads();
    const int p = tid >> 2;
    const int cs = (tid & 3) * 16;
    unsigned hw[8], lw[8];
#pragma unroll
    for (int k = 0; k < 8; ++k) {
        float x0 = T[cs + 2 * k][p], x1 = T[cs + 2 * k + 1][p];
        unsigned short a = f2bf(x0), c = f2bf(x1);
        hw[k] = (unsigned)a | ((unsigned)c << 16);
        unsigned short ra = f2bf(x0 - bf2f(a)), rc = f2bf(x1 - bf2f(c));
        lw[k] = (unsigned)ra | ((unsigned)rc << 16);
    }
    size_t base = (size_t)(p0 + p) * DD + cs;
    *(uint4*)(dh + base)     = make_uint4(hw[0], hw[1], hw[2], hw[3]);
    *(uint4*)(dh + base + 8) = make_uint4(hw[4], hw[5], hw[6], hw[7]);
    *(uint4*)(dl + base)     = make_uint4(lw[0], lw[1], lw[2], lw[3]);
    *(uint4*)(dl + base + 8) = make_uint4(lw[4], lw[5], lw[6], lw[7]);
}

__global__ void __launch_bounds__(256)
norms_kernel(const float* __restrict__ f0, const float* __restrict__ f1,
             float* __restrict__ n0, float* __restrict__ n1) {
    int t = blockIdx.x * 256 + threadIdx.x;
    if (t >= BB * MM) return;
    int b = t / MM, p = t % MM;
    const float* s0 = f0 + (size_t)b * DD * MM + p;
    const float* s1 = f1 + (size_t)b * DD * MM + p;
    float a = 0.f, c = 0.f;
#pragma unroll 8
    for (int k = 0; k < DD; ++k) {
        float x = s0[(size_t)k * MM]; a = fmaf(x, x, a);
        float y = s1[(size_t)k * MM]; c = fmaf(y, y, c);
    }
    n0[t] = a; n1[t] = c;
}

// ===========================================================================
// FAST PATH: build fp16 D once, stream it per pass
// ===========================================================================
__global__ void __launch_bounds__(256)
dist16_kernel(const unsigned short* __restrict__ h0, const unsigned short* __restrict__ l0,
              const unsigned short* __restrict__ h1, const unsigned short* __restrict__ l1,
              const float* __restrict__ n0, const float* __restrict__ n1,
              _Float16* __restrict__ D16) {
    const int id = blockIdx.x;
    const int xcd = id & 7, slot = id >> 3;
    const int b = xcd >> 1;
    const int x = slot * 2 + (xcd & 1);
    const int r0 = x * 32;
    const int tid = threadIdx.x;
    const int w = tid >> 6, l = tid & 63, lg = l >> 4, lc = l & 15;
    const size_t fb = (size_t)b * MM * DD;

    bf16x8 Ah[2][2], Al[2][2];
#pragma unroll
    for (int st = 0; st < 2; ++st) {
        const unsigned short* pa = h0 + fb + (size_t)(r0 + st * 16 + lc) * DD + 8 * lg;
        const unsigned short* qa = l0 + fb + (size_t)(r0 + st * 16 + lc) * DD + 8 * lg;
        Ah[st][0] = *(const bf16x8*)pa; Ah[st][1] = *(const bf16x8*)(pa + 32);
        Al[st][0] = *(const bf16x8*)qa; Al[st][1] = *(const bf16x8*)(qa + 32);
    }
    float n0r[2][4];
#pragma unroll
    for (int st = 0; st < 2; ++st)
#pragma unroll
        for (int e = 0; e < 4; ++e)
            n0r[st][e] = n0[b * MM + r0 + st * 16 + 4 * lg + e];

    for (int tt = 0; tt < 64; ++tt) {
        const int j0 = w * 1024 + tt * 16;
        const unsigned short* pb = h1 + fb + (size_t)(j0 + lc) * DD + 8 * lg;
        const unsigned short* qb = l1 + fb + (size_t)(j0 + lc) * DD + 8 * lg;
        bf16x8 Bh0 = *(const bf16x8*)pb, Bh1 = *(const bf16x8*)(pb + 32);
        bf16x8 Bl0 = *(const bf16x8*)qb, Bl1 = *(const bf16x8*)(qb + 32);
        float n1j = n1[b * MM + j0 + lc];
#pragma unroll
        for (int st = 0; st < 2; ++st) {
            f32x4 acc = {0.f, 0.f, 0.f, 0.f};
            acc = mfma16(Ah[st][0], Bh0, acc);
            acc = mfma16(Ah[st][1], Bh1, acc);
            acc = mfma16(Ah[st][0], Bl0, acc);
            acc = mfma16(Ah[st][1], Bl1, acc);
            acc = mfma16(Al[st][0], Bh0, acc);
            acc = mfma16(Al[st][1], Bh1, acc);
#pragma unroll
            for (int e = 0; e < 4; ++e) {
                float d2 = fmaxf(__builtin_fmaf(-2.f, acc[e], n0r[st][e] + n1j), 0.f);
                int row = r0 + st * 16 + 4 * lg + e;
                D16[((size_t)(b * MM + row)) * MM + j0 + lc] = (_Float16)sqrtf(d2);
            }
        }
    }
}

// u[b][i] = -NORMC - lse_j(d_ij + v_j); one wave per row, fixed-shift LSE
__global__ void __launch_bounds__(256)
u_pass_kernel(const _Float16* __restrict__ D16, const float* __restrict__ v,
              float* __restrict__ u, const float* __restrict__ bin) {
    const int tid = threadIdx.x;
    const int w = tid >> 6, l = tid & 63;
    const int blk = blockIdx.x;
    if (blk < BB * MM / 4) {
        const int row = blk * 4 + w;
        const int b = row >> 12, i = row & 4095;
        const float* vb = v + b * UVST;
        const _Float16* drow = D16 + (size_t)row * MM;
        float ss[8] = {};
#pragma unroll 2
        for (int st = 0; st < 8; ++st) {
            int j = st * 512 + l * 8;
            half8 dv = *(const half8*)(drow + j);
            float4 v0 = *(const float4*)(vb + j);
            float4 v1 = *(const float4*)(vb + j + 4);
            ss[0] += __expf((float)dv[0] + (v0.x - CSH));
            ss[1] += __expf((float)dv[1] + (v0.y - CSH));
            ss[2] += __expf((float)dv[2] + (v0.z - CSH));
            ss[3] += __expf((float)dv[3] + (v0.w - CSH));
            ss[4] += __expf((float)dv[4] + (v1.x - CSH));
            ss[5] += __expf((float)dv[5] + (v1.y - CSH));
            ss[6] += __expf((float)dv[6] + (v1.z - CSH));
            ss[7] += __expf((float)dv[7] + (v1.w - CSH));
        }
        float s = ((ss[0] + ss[1]) + (ss[2] + ss[3])) + ((ss[4] + ss[5]) + (ss[6] + ss[7]));
#pragma unroll
        for (int off = 1; off < 64; off <<= 1) s += __shfl_xor(s, off);
        if (l == 0) {
            s += __expf(*bin + v[b * UVST + MM] - CSH);   // dustbin column
            u[b * UVST + i] = -NORMC - CSH - __logf(s);
        }
    } else {
        // dustbin row: u[b][4096] = LOGHALF - bs - lse_j(v_j), exact online LSE
        const int b = blk - BB * MM / 4;
        float m = -INFINITY, s = 0.f;
        for (int t = tid; t < M1; t += 256) lse_add(m, s, v[b * UVST + t]);
#pragma unroll
        for (int off = 1; off < 64; off <<= 1)
            lse_merge(m, s, __shfl_xor(m, off), __shfl_xor(s, off));
        __shared__ float am[4], as_[4];
        if (l == 0) { am[w] = m; as_[w] = s; }
        __syncthreads();
        if (tid == 0) {
            float M = am[0], S = as_[0];
#pragma unroll
            for (int k = 1; k < 4; ++k) lse_merge(M, S, am[k], as_[k]);
            u[b * UVST + MM] = LOGHALF - (*bin) - (M + __logf(S));
        }
    }
}

// column partial sums over 32-row chunks: psum[b][chunk][j] = sum_i exp(d+u_i-CSH)
__global__ void __launch_bounds__(256)
v_part_kernel(const _Float16* __restrict__ D16, const float* __restrict__ u,
              float* __restrict__ psum) {
    const int blk = blockIdx.x;                 // 4 b x 128 chunk x 2 cg
    const int cg = blk & 1, chunk = (blk >> 1) & 127, b = blk >> 8;
    const int j0 = cg * 2048 + threadIdx.x * 8;
    const _Float16* dbase = D16 + ((size_t)(b * MM + chunk * 32)) * MM + j0;
    const float* ub = u + b * UVST + chunk * 32;
    float s[8] = {};
    for (int r = 0; r < 32; ++r) {
        float uu = ub[r] - CSH;
        half8 dv = *(const half8*)(dbase + (size_t)r * MM);
#pragma unroll
        for (int k = 0; k < 8; ++k) s[k] += __expf((float)dv[k] + uu);
    }
    float* po = psum + ((size_t)(b * 128 + chunk)) * MM + j0;
    *(float4*)po       = make_float4(s[0], s[1], s[2], s[3]);
    *(float4*)(po + 4) = make_float4(s[4], s[5], s[6], s[7]);
}

__global__ void __launch_bounds__(256)
v_comb_kernel(const float* __restrict__ psum, const float* __restrict__ u,
              float* __restrict__ v, const float* __restrict__ bin) {
    const int tid = threadIdx.x;
    const int blk = blockIdx.x;
    if (blk < 64) {
        int t = blk * 256 + tid;                 // over BB*MM
        int b = t >> 12, j = t & 4095;
        const float* pp = psum + (size_t)b * 128 * MM + j;
        float S = 0.f;
#pragma unroll 8
        for (int c = 0; c < 128; ++c) S += pp[(size_t)c * MM];
        S += __expf(*bin + u[b * UVST + MM] - CSH);   // dustbin row
        v[b * UVST + j] = -NORMC - CSH - __logf(S);
    } else {
        // dustbin col: v[b][4096] = LOGHALF - bs - lse_i(u_i), exact
        const int b = blk - 64;
        const int w = tid >> 6, l = tid & 63;
        float m = -INFINITY, s = 0.f;
        for (int t = tid; t < M1; t += 256) lse_add(m, s, u[b * UVST + t]);
#pragma unroll
        for (int off = 1; off < 64; off <<= 1)
            lse_merge(m, s, __shfl_xor(m, off), __shfl_xor(s, off));
        __shared__ float am[4], as_[4];
        if (l == 0) { am[w] = m; as_[w] = s; }
        __syncthreads();
        if (tid == 0) {
            float M = am[0], S = as_[0];
#pragma unroll
            for (int k = 1; k < 4; ++k) lse_merge(M, S, am[k], as_[k]);
            v[b * UVST + MM] = LOGHALF - (*bin) - (M + __logf(S));
        }
    }
}

// gamma main block: coalesced elementwise (lane-per-column), loss partials
__global__ void __launch_bounds__(256)
fin_kernel(const _Float16* __restrict__ D16, const float* __restrict__ u,
           const float* __restrict__ v, float* __restrict__ G,
           float* __restrict__ pA) {
    const int tid = threadIdx.x;
    const int w = tid >> 6, l = tid & 63;
    const int row = blockIdx.x * 4 + w;
    const int b = row >> 12, i = row & 4095;
    const float* vb = v + b * UVST;
    const float cu = u[b * UVST + i] + NORMC;
    const _Float16* drow = D16 + (size_t)row * MM;
    float* grow = G + ((size_t)(b * M1 + i)) * M1;
    float pm = 0.f, pr = 0.f;
    for (int it = 0; it < 64; ++it) {
        int j = it * 64 + l;
        float d = (float)drow[j];
        float g = __expf(d + vb[j] + cu);
        grow[j] = g;
        pm = fmaf(g, d, pm);
        pr += g;
    }
#pragma unroll
    for (int off = 1; off < 64; off <<= 1) {
        pm += __shfl_xor(pm, off);
        pr += __shfl_xor(pr, off);
    }
    __shared__ float s0[4], s1[4];
    if (l == 0) { s0[w] = pm; s1[w] = pr; }
    __syncthreads();
    if (tid == 0) {
        pA[blockIdx.x * 2 + 0] = s0[0] + s0[1] + s0[2] + s0[3];
        pA[blockIdx.x * 2 + 1] = s1[0] + s1[1] + s1[2] + s1[3];
    }
}

// last row + last col + corner of gamma (uvst parameterized for both paths)
__global__ void __launch_bounds__(256)
fin_edge_kernel(const float* __restrict__ u, const float* __restrict__ v,
                const float* __restrict__ bin, float* __restrict__ G,
                float* __restrict__ pB, int uvst) {
    const float bs = *bin;
    int t = blockIdx.x * 256 + threadIdx.x;
    float pc = 0.f, pr = 0.f;
    if (t < BB * M1) {
        int b = t / M1, j = t % M1;
        float g = __expf(bs + u[b * uvst + MM] + v[b * uvst + j] + NORMC);
        G[((size_t)b * M1 + MM) * M1 + j] = g;
        if (j == MM) pc += g;
    } else if (t < BB * M1 + BB * MM) {
        int q = t - BB * M1;
        int b = q / MM, i = q % MM;
        float g = __expf(bs + u[b * uvst + i] + v[b * uvst + MM] + NORMC);
        G[((size_t)b * M1 + i) * M1 + MM] = g;
        pc += g; pr += g;
    }
#pragma unroll
    for (int off = 1; off < 64; off <<= 1) {
        pc += __shfl_xor(pc, off);
        pr += __shfl_xor(pr, off);
    }
    __shared__ float s0[4], s1[4];
    int tid = threadIdx.x;
    if ((tid & 63) == 0) { s0[tid >> 6] = pc; s1[tid >> 6] = pr; }
    __syncthreads();
    if (tid == 0) {
        pB[blockIdx.x * 2 + 0] = s0[0] + s0[1] + s0[2] + s0[3];
        pB[blockIdx.x * 2 + 1] = s1[0] + s1[1] + s1[2] + s1[3];
    }
}

__global__ void __launch_bounds__(256)
reduce_out_kernel(const float* __restrict__ pA, int nA,
                  const float* __restrict__ pB, int nB, float* __restrict__ out) {
    const int tid = threadIdx.x;
    float pm = 0.f, prA = 0.f, pc = 0.f, prB = 0.f;
    for (int r = tid; r < nA; r += 256) { pm += pA[2 * r]; prA += pA[2 * r + 1]; }
    for (int r = tid; r < nB; r += 256) { pc += pB[2 * r]; prB += pB[2 * r + 1]; }
#pragma unroll
    for (int off = 1; off < 64; off <<= 1) {
        pm += __shfl_xor(pm, off);
        prA += __shfl_xor(prA, off);
        pc += __shfl_xor(pc, off);
        prB += __shfl_xor(prB, off);
    }
    __shared__ float a0[4], a1[4], a2[4], a3[4];
    if ((tid & 63) == 0) {
        int w = tid >> 6;
        a0[w] = pm; a1[w] = prA; a2[w] = pc; a3[w] = prB;
    }
    __syncthreads();
    if (tid == 0) {
        float PM = a0[0] + a0[1] + a0[2] + a0[3];
        float PRA = a1[0] + a1[1] + a1[2] + a1[3];
        float PC = a2[0] + a2[1] + a2[2] + a2[3];
        float PRB = a3[0] + a3[1] + a3[2] + a3[3];
        out[0] = PM / (4.0f * 4096.0f);
        out[1] = PC / (4.0f * 4097.0f) + (PRA + PRB) / (4.0f * 4096.0f * 4097.0f);
    }
}

// ===========================================================================
// FALLBACK (round-2 recompute path, ~8.7 MB ws) — used only if ws too small
// ===========================================================================
__global__ void __launch_bounds__(256)
upass_kernel(const unsigned short* __restrict__ h0, const unsigned short* __restrict__ l0,
             const unsigned short* __restrict__ h1, const unsigned short* __restrict__ l1,
             const float* __restrict__ n0, const float* __restrict__ n1,
             const float* __restrict__ v, float* __restrict__ u,
             const float* __restrict__ bin) {
    const int id = blockIdx.x;
    const int xcd = id & 7, slot = id >> 3;
    const int b = xcd >> 1;
    const int x = slot * 2 + (xcd & 1);
    const int r0 = x * 32;
    const float bs = *bin;
    const float* vb = v + b * M1;
    const int tid = threadIdx.x;
    const int w = tid >> 6, l = tid & 63, lg = l >> 4, lc = l & 15;
    const size_t fb = (size_t)b * MM * DD;
    bf16x8 Ah[2][2], Al[2][2];
#pragma unroll
    for (int st = 0; st < 2; ++st) {
        const unsigned short* pa = h0 + fb + (size_t)(r0 + st * 16 + lc) * DD + 8 * lg;
        const unsigned short* qa = l0 + fb + (size_t)(r0 + st * 16 + lc) * DD + 8 * lg;
        Ah[st][0] = *(const bf16x8*)pa; Ah[st][1] = *(const bf16x8*)(pa + 32);
        Al[st][0] = *(const bf16x8*)qa; Al[st][1] = *(const bf16x8*)(qa + 32);
    }
    float n0r[2][4], m[2][4], s[2][4];
#pragma unroll
    for (int st = 0; st < 2; ++st)
#pragma unroll
        for (int e = 0; e < 4; ++e) {
            n0r[st][e] = n0[b * MM + r0 + st * 16 + 4 * lg + e];
            m[st][e] = -INFINITY; s[st][e] = 0.f;
        }
    for (int tt = 0; tt < 64; ++tt) {
        const int j0 = w * 1024 + tt * 16;
        const unsigned short* pb = h1 + fb + (size_t)(j0 + lc) * DD + 8 * lg;
        const unsigned short* qb = l1 + fb + (size_t)(j0 + lc) * DD + 8 * lg;
        bf16x8 Bh0 = *(const bf16x8*)pb, Bh1 = *(const bf16x8*)(pb + 32);
        bf16x8 Bl0 = *(const bf16x8*)qb, Bl1 = *(const bf16x8*)(qb + 32);
        float n1j = n1[b * MM + j0 + lc];
        float vj = vb[j0 + lc];
#pragma unroll
        for (int st = 0; st < 2; ++st) {
            f32x4 acc = {0.f, 0.f, 0.f, 0.f};
            acc = mfma16(Ah[st][0], Bh0, acc);
            acc = mfma16(Ah[st][1], Bh1, acc);
            acc = mfma16(Ah[st][0], Bl0, acc);
            acc = mfma16(Ah[st][1], Bl1, acc);
            acc = mfma16(Al[st][0], Bh0, acc);
            acc = mfma16(Al[st][1], Bh1, acc);
#pragma unroll
            for (int e = 0; e < 4; ++e) {
                float d2 = fmaxf(__builtin_fmaf(-2.f, acc[e], n0r[st][e] + n1j), 0.f);
                lse_add(m[st][e], s[st][e], sqrtf(d2) + vj);
            }
        }
    }
#pragma unroll
    for (int off = 1; off < 16; off <<= 1)
#pragma unroll
        for (int st = 0; st < 2; ++st)
#pragma unroll
            for (int e = 0; e < 4; ++e)
                lse_merge(m[st][e], s[st][e], __shfl_xor(m[st][e], off), __shfl_xor(s[st][e], off));
    __shared__ float lm[4][32], lsx[4][32];
    if (lc == 0) {
#pragma unroll
        for (int st = 0; st < 2; ++st)
#pragma unroll
            for (int e = 0; e < 4; ++e) {
                lm[w][st * 16 + 4 * lg + e] = m[st][e];
                lsx[w][st * 16 + 4 * lg + e] = s[st][e];
            }
    }
    __syncthreads();
    if (tid < 32) {
        float M = lm[0][tid], S = lsx[0][tid];
#pragma unroll
        for (int k = 1; k < 4; ++k) lse_merge(M, S, lm[k][tid], lsx[k][tid]);
        lse_add(M, S, bs + vb[MM]);
        u[b * M1 + r0 + tid] = -NORMC - (M + __logf(S));
    }
    if (x == 0) {
        float dm = -INFINITY, dsv = 0.f;
        for (int j = tid; j < M1; j += 256) lse_add(dm, dsv, vb[j]);
#pragma unroll
        for (int off = 1; off < 64; off <<= 1)
            lse_merge(dm, dsv, __shfl_xor(dm, off), __shfl_xor(dsv, off));
        __shared__ float am[4], asv[4];
        if (l == 0) { am[w] = dm; asv[w] = dsv; }
        __syncthreads();
        if (tid == 0) {
            float M = am[0], S = asv[0];
#pragma unroll
            for (int k = 1; k < 4; ++k) lse_merge(M, S, am[k], asv[k]);
            u[b * M1 + MM] = LOGHALF - (bs + M + __logf(S));
        }
    }
}

__global__ void __launch_bounds__(256)
vpass_kernel(const unsigned short* __restrict__ h0, const unsigned short* __restrict__ l0,
             const unsigned short* __restrict__ h1, const unsigned short* __restrict__ l1,
             const float* __restrict__ n0, const float* __restrict__ n1,
             const float* __restrict__ u, float* __restrict__ v,
             const float* __restrict__ bin) {
    const int id = blockIdx.x;
    const int xcd = id & 7, slot = id >> 3;
    const int b = xcd >> 1;
    const int x = slot * 2 + (xcd & 1);
    const int j0 = x * 32;
    const float bs = *bin;
    const float* ub = u + b * M1;
    const int tid = threadIdx.x;
    const int w = tid >> 6, l = tid & 63, lg = l >> 4, lc = l & 15;
    const size_t fb = (size_t)b * MM * DD;
    bf16x8 Bh[2][2], Bl[2][2];
#pragma unroll
    for (int st = 0; st < 2; ++st) {
        const unsigned short* pb = h1 + fb + (size_t)(j0 + st * 16 + lc) * DD + 8 * lg;
        const unsigned short* qb = l1 + fb + (size_t)(j0 + st * 16 + lc) * DD + 8 * lg;
        Bh[st][0] = *(const bf16x8*)pb; Bh[st][1] = *(const bf16x8*)(pb + 32);
        Bl[st][0] = *(const bf16x8*)qb; Bl[st][1] = *(const bf16x8*)(qb + 32);
    }
    float n1c[2] = { n1[b * MM + j0 + lc], n1[b * MM + j0 + 16 + lc] };
    float m[2] = { -INFINITY, -INFINITY }, s[2] = { 0.f, 0.f };
    for (int tt = 0; tt < 64; ++tt) {
        const int i0 = w * 1024 + tt * 16;
        const unsigned short* pa = h0 + fb + (size_t)(i0 + lc) * DD + 8 * lg;
        const unsigned short* qa = l0 + fb + (size_t)(i0 + lc) * DD + 8 * lg;
        bf16x8 Ah0 = *(const bf16x8*)pa, Ah1 = *(const bf16x8*)(pa + 32);
        bf16x8 Al0 = *(const bf16x8*)qa, Al1 = *(const bf16x8*)(qa + 32);
        float uw[4], nw[4];
#pragma unroll
        for (int e = 0; e < 4; ++e) {
            int row = i0 + 4 * lg + e;
            uw[e] = ub[row];
            nw[e] = n0[b * MM + row];
        }
#pragma unroll
        for (int st = 0; st < 2; ++st) {
            f32x4 acc = {0.f, 0.f, 0.f, 0.f};
            acc = mfma16(Ah0, Bh[st][0], acc);
            acc = mfma16(Ah1, Bh[st][1], acc);
            acc = mfma16(Ah0, Bl[st][0], acc);
            acc = mfma16(Ah1, Bl[st][1], acc);
            acc = mfma16(Al0, Bh[st][0], acc);
            acc = mfma16(Al1, Bh[st][1], acc);
#pragma unroll
            for (int e = 0; e < 4; ++e) {
                float d2 = fmaxf(__builtin_fmaf(-2.f, acc[e], nw[e] + n1c[st]), 0.f);
                lse_add(m[st], s[st], sqrtf(d2) + uw[e]);
            }
        }
    }
#pragma unroll
    for (int off = 16; off < 64; off <<= 1)
#pragma unroll
        for (int st = 0; st < 2; ++st)
            lse_merge(m[st], s[st], __shfl_xor(m[st], off), __shfl_xor(s[st], off));
    __shared__ float lmv[4][2][16], lsv[4][2][16];
    if (l < 16) {
#pragma unroll
        for (int st = 0; st < 2; ++st) { lmv[w][st][l] = m[st]; lsv[w][st][l] = s[st]; }
    }
    __syncthreads();
    if (tid < 32) {
        int st = tid >> 4, c = tid & 15;
        float M = lmv[0][st][c], S = lsv[0][st][c];
#pragma unroll
        for (int k = 1; k < 4; ++k) lse_merge(M, S, lmv[k][st][c], lsv[k][st][c]);
        lse_add(M, S, bs + ub[MM]);
        v[b * M1 + j0 + st * 16 + c] = -NORMC - (M + __logf(S));
    }
    if (x == 0) {
        float dm = -INFINITY, dsv = 0.f;
        for (int i = tid; i < M1; i += 256) lse_add(dm, dsv, ub[i]);
#pragma unroll
        for (int off = 1; off < 64; off <<= 1)
            lse_merge(dm, dsv, __shfl_xor(dm, off), __shfl_xor(dsv, off));
        __shared__ float am[4], asv[4];
        if (l == 0) { am[w] = dm; asv[w] = dsv; }
        __syncthreads();
        if (tid == 0) {
            float M = am[0], S = asv[0];
#pragma unroll
            for (int k = 1; k < 4; ++k) lse_merge(M, S, am[k], asv[k]);
            v[b * M1 + MM] = LOGHALF - (bs + M + __logf(S));
        }
    }
}

__global__ void __launch_bounds__(256)
fin_rec_kernel(const unsigned short* __restrict__ h0, const unsigned short* __restrict__ l0,
               const unsigned short* __restrict__ h1, const unsigned short* __restrict__ l1,
               const float* __restrict__ n0, const float* __restrict__ n1,
               const float* __restrict__ u, const float* __restrict__ v,
               float* __restrict__ G, float* __restrict__ pA) {
    const int id = blockIdx.x;
    const int xcd = id & 7, slot = id >> 3;
    const int b = xcd >> 1;
    const int x = slot * 2 + (xcd & 1);
    const int r0 = x * 32;
    const float* vb = v + b * M1;
    const int tid = threadIdx.x;
    const int w = tid >> 6, l = tid & 63, lg = l >> 4, lc = l & 15;
    const size_t fb = (size_t)b * MM * DD;
    bf16x8 Ah[2][2], Al[2][2];
#pragma unroll
    for (int st = 0; st < 2; ++st) {
        const unsigned short* pa = h0 + fb + (size_t)(r0 + st * 16 + lc) * DD + 8 * lg;
        const unsigned short* qa = l0 + fb + (size_t)(r0 + st * 16 + lc) * DD + 8 * lg;
        Ah[st][0] = *(const bf16x8*)pa; Ah[st][1] = *(const bf16x8*)(pa + 32);
        Al[st][0] = *(const bf16x8*)qa; Al[st][1] = *(const bf16x8*)(qa + 32);
    }
    float n0r[2][4], ur[2][4];
#pragma unroll
    for (int st = 0; st < 2; ++st)
#pragma unroll
        for (int e = 0; e < 4; ++e) {
            int row = r0 + st * 16 + 4 * lg + e;
            n0r[st][e] = n0[b * MM + row];
            ur[st][e] = u[b * M1 + row];
        }
    float pm = 0.f, pr = 0.f;
    for (int tt = 0; tt < 64; ++tt) {
        const int j0 = w * 1024 + tt * 16;
        const unsigned short* pb = h1 + fb + (size_t)(j0 + lc) * DD + 8 * lg;
        const unsigned short* qb = l1 + fb + (size_t)(j0 + lc) * DD + 8 * lg;
        bf16x8 Bh0 = *(const bf16x8*)pb, Bh1 = *(const bf16x8*)(pb + 32);
        bf16x8 Bl0 = *(const bf16x8*)qb, Bl1 = *(const bf16x8*)(qb + 32);
        float n1j = n1[b * MM + j0 + lc];
        float vj = vb[j0 + lc];
#pragma unroll
        for (int st = 0; st < 2; ++st) {
            f32x4 acc = {0.f, 0.f, 0.f, 0.f};
            acc = mfma16(Ah[st][0], Bh0, acc);
            acc = mfma16(Ah[st][1], Bh1, acc);
            acc = mfma16(Ah[st][0], Bl0, acc);
            acc = mfma16(Ah[st][1], Bl1, acc);
            acc = mfma16(Al[st][0], Bh0, acc);
            acc = mfma16(Al[st][1], Bh1, acc);
#pragma unroll
            for (int e = 0; e < 4; ++e) {
                float d2 = fmaxf(__builtin_fmaf(-2.f, acc[e], n0r[st][e] + n1j), 0.f);
                float d = sqrtf(d2);
                float g = __expf(d + ur[st][e] + vj + NORMC);
                int row = r0 + st * 16 + 4 * lg + e;
                G[((size_t)(b * M1 + row)) * M1 + j0 + lc] = g;
                pm = fmaf(g, d, pm);
                pr += g;
            }
        }
    }
#pragma unroll
    for (int off = 1; off < 64; off <<= 1) {
        pm += __shfl_xor(pm, off);
        pr += __shfl_xor(pr, off);
    }
    __shared__ float s0[4], s1[4];
    if (l == 0) { s0[w] = pm; s1[w] = pr; }
    __syncthreads();
    if (tid == 0) {
        pA[id * 2 + 0] = s0[0] + s0[1] + s0[2] + s0[3];
        pA[id * 2 + 1] = s1[0] + s1[1] + s1[2] + s1[3];
    }
}

// ===========================================================================
extern "C" void kernel_launch(void* const* d_in, const int* in_sizes, int n_in,
                              void* d_out, int out_size, void* d_ws, size_t ws_size,
                              hipStream_t stream) {
    const float* feat0 = (const float*)d_in[0];
    const float* feat1 = (const float*)d_in[1];
    const float* bin   = (const float*)d_in[2];
    float* out = (float*)d_out;
    float* G   = out + 2;                      // gamma region [4][4097][4097]
    float* ws  = (float*)d_ws;

    // fast-path ws layout (float offsets)
    const size_t OF_U = 0;                      // 4*4104
    const size_t OF_V = 16416;                  // 4*4104
    const size_t OF_N0 = 32832;                 // 16384
    const size_t OF_N1 = 49216;                 // 16384
    const size_t OF_PA = 65600;                 // 8192
    const size_t OF_PB = 73792;                 // 260
    const size_t OF_PSUM = 74052;               // 4*128*4096
    const size_t OF_BF = 2171204;               // 4 x 1M ushorts
    const size_t OF_D16 = 4268356;              // 64M ushorts
    const size_t NEED = (OF_D16 + 33554432) * 4;

    if (ws_size >= NEED) {
        float* u  = ws + OF_U;
        float* v  = ws + OF_V;
        float* n0 = ws + OF_N0;
        float* n1 = ws + OF_N1;
        float* pA = ws + OF_PA;
        float* pB = ws + OF_PB;
        float* psum = ws + OF_PSUM;
        unsigned short* h0 = (unsigned short*)(ws + OF_BF);
        unsigned short* l0 = h0 + 1048576;
        unsigned short* h1 = l0 + 1048576;
        unsigned short* l1 = h1 + 1048576;
        _Float16* D16 = (_Float16*)(ws + OF_D16);

        hipMemsetAsync(ws, 0, 32832 * sizeof(float), stream);   // u, v = 0
        prep_kernel<<<dim3(64, BB, 2), 256, 0, stream>>>(feat0, feat1, h0, l0, h1, l1);
        norms_kernel<<<64, 256, 0, stream>>>(feat0, feat1, n0, n1);
        dist16_kernel<<<512, 256, 0, stream>>>(h0, l0, h1, l1, n0, n1, D16);
        for (int it = 0; it < 10; ++it) {
            u_pass_kernel<<<BB * MM / 4 + BB, 256, 0, stream>>>(D16, v, u, bin);
            v_part_kernel<<<1024, 256, 0, stream>>>(D16, u, psum);
            v_comb_kernel<<<64 + BB, 256, 0, stream>>>(psum, u, v, bin);
        }
        fin_kernel<<<4096, 256, 0, stream>>>(D16, u, v, G, pA);
        fin_edge_kernel<<<129, 256, 0, stream>>>(u, v, bin, G, pB, UVST);
        reduce_out_kernel<<<1, 256, 0, stream>>>(pA, 4096, pB, 129, out);
    } else {
        // fallback: round-2 recompute path (~8.7 MB ws)
        float* u  = ws;                          // 16388
        float* v  = ws + 16388;                  // 16388
        float* n0 = ws + 32776;                  // 16384
        float* n1 = ws + 49160;                  // 16384
        float* pA = ws + 65544;                  // 1024
        float* pB = ws + 66568;                  // 264
        unsigned short* h0 = (unsigned short*)(ws + 66832);
        unsigned short* l0 = h0 + 1048576;
        unsigned short* h1 = l0 + 1048576;
        unsigned short* l1 = h1 + 1048576;

        hipMemsetAsync(ws, 0, 32776 * sizeof(float), stream);
        prep_kernel<<<dim3(64, BB, 2), 256, 0, stream>>>(feat0, feat1, h0, l0, h1, l1);
        norms_kernel<<<64, 256, 0, stream>>>(feat0, feat1, n0, n1);
        for (int it = 0; it < 10; ++it) {
            upass_kernel<<<512, 256, 0, stream>>>(h0, l0, h1, l1, n0, n1, v, u, bin);
            vpass_kernel<<<512, 256, 0, stream>>>(h0, l0, h1, l1, n0, n1, u, v, bin);
        }
        fin_rec_kernel<<<512, 256, 0, stream>>>(h0, l0, h1, l1, n0, n1, u, v, G, pA);
        fin_edge_kernel<<<129, 256, 0, stream>>>(u, v, bin, G, pB, M1);
        reduce_out_kernel<<<1, 256, 0, stream>>>(pA, 512, pB, 129, out);
    }
}